// Round 5
// baseline (80.476 us; speedup 1.0000x reference)
//
#include <hip/hip_runtime.h>

// softmax(ALPHA*|x-bins|) over K=32 bins + weighted-sum code.
// Memory-bound: ~286 MB traffic; fillBuffer on this chip: 7.0 TB/s -> ~41us floor.
// R4: one THREAD per element. 32 bins in registers as 16 packed f32x2
//     (v_pk math), no cross-lane reductions at all, x loaded once/element,
//     code stored dense 256B/wave. Weights go through a padded wave-local
//     LDS transpose (no barriers) so global stores remain fully coalesced
//     16B/lane, 64B-sector-complete.

#define SSQ_SCALE (-432.80854f)   // ALPHA * log2(e)

typedef float f32x2 __attribute__((ext_vector_type(2)));
typedef float f32x4 __attribute__((ext_vector_type(4)));

// Per wave: 2 halves x 64 rows x 17 floats (16 weights + 1 pad) = 2176 floats.
// Block (4 waves): 8704 floats = 34816 B -> 4 blocks/CU LDS-wise.

__global__ __launch_bounds__(256) void ssq_kernel(
    const float* __restrict__ x,      // n elements
    const float* __restrict__ bins,   // K = 32
    float* __restrict__ soft,         // n*32
    float* __restrict__ code,         // n
    int n)
{
    __shared__ float lds[4 * 2 * 64 * 17];

    const int tid  = threadIdx.x;
    const int wave = tid >> 6;
    const int lane = tid & 63;
    const int e    = blockIdx.x * 256 + tid;      // exact cover: n % 256 == 0

    float* __restrict__ wlds = &lds[wave * (2 * 64 * 17)];
    f32x4* __restrict__ soft4 = reinterpret_cast<f32x4*>(soft);

    // ---- bins as 16 packed pairs (wave-uniform)
    f32x2 b[16];
    #pragma unroll
    for (int i = 0; i < 16; ++i)
        b[i] = reinterpret_cast<const f32x2*>(bins)[i];

    const float xv = x[e];                        // coalesced 4B/lane
    const f32x2 x2 = {xv, xv};

    // ---- packed |x - b|
    f32x2 d[16];
    #pragma unroll
    for (int i = 0; i < 16; ++i)
        d[i] = __builtin_elementwise_abs(x2 - b[i]);

    // ---- dmin via packed min tree
    f32x2 m8[8];
    #pragma unroll
    for (int i = 0; i < 8; ++i) m8[i] = __builtin_elementwise_min(d[i], d[i + 8]);
    #pragma unroll
    for (int i = 0; i < 4; ++i) m8[i] = __builtin_elementwise_min(m8[i], m8[i + 4]);
    m8[0] = __builtin_elementwise_min(m8[0], m8[2]);
    m8[1] = __builtin_elementwise_min(m8[1], m8[3]);
    m8[0] = __builtin_elementwise_min(m8[0], m8[1]);
    const float dmin = fminf(m8[0].x, m8[0].y);

    // ---- e_k = exp2(SCALE*(d - dmin)); joint sum and weighted-bin numerator
    const float moff = -SSQ_SCALE * dmin;         // s = SCALE*d + moff <= 0
    const f32x2 sc  = {SSQ_SCALE, SSQ_SCALE};
    const f32x2 off = {moff, moff};
    f32x2 acc_s = {0.0f, 0.0f};
    f32x2 acc_n = {0.0f, 0.0f};
    #pragma unroll
    for (int i = 0; i < 16; ++i) {
        const f32x2 s = d[i] * sc + off;          // pk_fma
        f32x2 ev;
        ev.x = exp2f(s.x);
        ev.y = exp2f(s.y);
        d[i] = ev;                                // reuse as weights
        acc_s += ev;
        acc_n += ev * b[i];                       // pk_fma
    }
    const float sum = acc_s.x + acc_s.y;
    const float num = acc_n.x + acc_n.y;
    const float inv = __builtin_amdgcn_rcpf(sum);

    code[e] = num * inv;                          // dense 4B/lane

    const f32x2 inv2 = {inv, inv};
    #pragma unroll
    for (int i = 0; i < 16; ++i) d[i] *= inv2;

    // ---- wave-local LDS transpose (both halves), then dense global stores.
    // write: row = lane (17-float pitch -> banks (lane + 16*(lane&1) + 4q): 2-way max)
    #pragma unroll
    for (int h = 0; h < 2; ++h) {
        #pragma unroll
        for (int q = 0; q < 4; ++q) {
            f32x4 v;
            v.x = d[h * 8 + 2 * q].x;
            v.y = d[h * 8 + 2 * q].y;
            v.z = d[h * 8 + 2 * q + 1].x;
            v.w = d[h * 8 + 2 * q + 1].y;
            *reinterpret_cast<f32x4*>(&wlds[h * 1088 + lane * 17 + q * 4]) = v;
        }
    }
    // read transposed + store: lane j handles quad (r*64+j) of this wave's 512
    const int wq_base = (blockIdx.x * 256 + wave * 64) * 8;   // wave's first quad
    #pragma unroll
    for (int h = 0; h < 2; ++h) {
        #pragma unroll
        for (int r = 0; r < 4; ++r) {
            const int lq = r * 64 + lane;         // 0..255 within half
            const int le = lq >> 2;               // local element 0..63
            const int q  = lq & 3;                // quad within half
            const f32x4 v = *reinterpret_cast<const f32x4*>(
                &wlds[h * 1088 + le * 17 + q * 4]);
            soft4[wq_base + le * 8 + h * 4 + q] = v;   // 64B-sector-complete
        }
    }
}

extern "C" void kernel_launch(void* const* d_in, const int* in_sizes, int n_in,
                              void* d_out, int out_size, void* d_ws, size_t ws_size,
                              hipStream_t stream) {
    const float* x    = (const float*)d_in[0];   // (B, L, 1) f32
    const float* bins = (const float*)d_in[1];   // (K,) f32, K == 32
    const int n = in_sizes[0];                   // B*L = 2,097,152 (mult of 256)

    float* soft = (float*)d_out;                 // (B, L, 32)
    float* code = soft + (size_t)n * 32;         // (B, L, 1)

    const int block = 256;
    const int grid  = n / block;                 // exact cover, no tail
    ssq_kernel<<<grid, block, 0, stream>>>(x, bins, soft, code, n);
}